// Round 1
// baseline (253.717 us; speedup 1.0000x reference)
//
#include <hip/hip_runtime.h>

// x: (8, 64, 256, 256) fp32; alpha: (1,64,1,1) fp32
// out = x + alpha[c] * sum_{3x3 zero-padded} |x - neighbor|
// Memory-bound: 268 MB min traffic -> ~43 us floor at 6.3 TB/s.

constexpr int H = 256;
constexpr int W = 256;
constexpr int C = 64;

__global__ __launch_bounds__(256) void adc_kernel(
    const float* __restrict__ x,
    const float* __restrict__ alpha,
    float* __restrict__ out)
{
    // 64 float4-groups per row; thread -> (row, group)
    const long tid = (long)blockIdx.x * blockDim.x + threadIdx.x;
    const long row = tid >> 6;      // / 64
    const int  g   = (int)(tid & 63);
    const int  y   = (int)(row & (H - 1));
    const long bc  = row >> 8;      // / H
    const int  c   = (int)(bc & (C - 1));

    const float* img  = x   + bc * (long)(H * W);
    float*       outp = out + bc * (long)(H * W);
    const float  a    = alpha[c];
    const int    w0   = g * 4;

    // 3 rows x 6 cols of neighborhood (zero-padded)
    float v[3][6];
#pragma unroll
    for (int r = 0; r < 3; ++r) {
        const int yy = y + r - 1;
        if (yy < 0 || yy >= H) {
#pragma unroll
            for (int j = 0; j < 6; ++j) v[r][j] = 0.f;
        } else {
            const float* rowp = img + (long)yy * W + w0;
            const float4 ctr = *(const float4*)rowp;
            v[r][1] = ctr.x; v[r][2] = ctr.y; v[r][3] = ctr.z; v[r][4] = ctr.w;
            v[r][0] = (w0 > 0)     ? rowp[-1] : 0.f;
            v[r][5] = (w0 + 4 < W) ? rowp[4]  : 0.f;
        }
    }

    float4 res;
    float* rp = &res.x;
#pragma unroll
    for (int j = 0; j < 4; ++j) {
        const float xc = v[1][j + 1];
        float s = 0.f;
#pragma unroll
        for (int r = 0; r < 3; ++r)
#pragma unroll
            for (int d = 0; d < 3; ++d)
                s += fabsf(xc - v[r][j + d]);
        rp[j] = fmaf(a, s, xc);
    }
    *(float4*)(outp + (long)y * W + w0) = res;
}

extern "C" void kernel_launch(void* const* d_in, const int* in_sizes, int n_in,
                              void* d_out, int out_size, void* d_ws, size_t ws_size,
                              hipStream_t stream)
{
    const float* x     = (const float*)d_in[0];
    const float* alpha = (const float*)d_in[1];
    float*       out   = (float*)d_out;

    const long total_rows    = 8L * C * H;        // 131072
    const long total_threads = total_rows * (W / 4); // 8.39M
    const int  block = 256;
    const long grid  = (total_threads + block - 1) / block;

    adc_kernel<<<(int)grid, block, 0, stream>>>(x, alpha, out);
}

// Round 2
// 234.704 us; speedup vs baseline: 1.0810x; 1.0810x over previous
//
#include <hip/hip_runtime.h>

// x: (8, 64, 256, 256) fp32; alpha: (1,64,1,1) fp32
// out = x + alpha[c] * sum_{3x3 zero-padded} |x - neighbor|
//
// One wave (64 lanes x float4) = one full 256-wide row.
// Each wave computes 4 output rows from 6 loaded rows (register halo reuse).
// Left/right halo via __shfl (lane 0/63 -> 0 == the zero padding).
// Block = 4 waves = 16-row slab. Grid = 512 images * 16 slabs = 8192 blocks.

constexpr int H = 256;
constexpr int W = 256;
constexpr int C = 64;

__global__ __launch_bounds__(256) void adc_kernel(
    const float* __restrict__ x,
    const float* __restrict__ alpha,
    float* __restrict__ out)
{
    const int lane = threadIdx.x & 63;
    const int wave = threadIdx.x >> 6;            // 0..3
    const long slab = (long)blockIdx.x;           // img*16 + slab16
    const long img  = slab >> 4;                  // 0..511 (b*C + c)
    const int  s16  = (int)(slab & 15);
    const int  y0   = s16 * 16 + wave * 4;        // first output row of this wave
    const int  c    = (int)(img & (C - 1));

    const float  a    = alpha[c];
    const float* imgp = x   + img * (long)(H * W);
    float*       outp = out + img * (long)(H * W);
    const int    w0   = lane * 4;

    // Load 6 rows x 6 cols window (rows y0-1 .. y0+4), zero-padded.
    float v[6][6];
#pragma unroll
    for (int r = 0; r < 6; ++r) {
        const int yy = y0 + r - 1;
        float4 ctr = make_float4(0.f, 0.f, 0.f, 0.f);
        if (yy >= 0 && yy < H)
            ctr = *(const float4*)(imgp + (long)yy * W + w0);
        v[r][1] = ctr.x; v[r][2] = ctr.y; v[r][3] = ctr.z; v[r][4] = ctr.w;
        const float left  = __shfl_up(ctr.w, 1);
        const float right = __shfl_down(ctr.x, 1);
        v[r][0] = (lane == 0)  ? 0.f : left;    // w0==0 edge -> zero pad
        v[r][5] = (lane == 63) ? 0.f : right;   // w0+4==W edge -> zero pad
    }

    // 4 output rows, 4 cols each.
#pragma unroll
    for (int o = 0; o < 4; ++o) {
        float4 res;
        float* rp = &res.x;
#pragma unroll
        for (int j = 0; j < 4; ++j) {
            const float xc = v[o + 1][j + 1];
            float s = 0.f;
#pragma unroll
            for (int r = 0; r < 3; ++r)
#pragma unroll
                for (int d = 0; d < 3; ++d)
                    s += fabsf(xc - v[o + r][j + d]);
            rp[j] = fmaf(a, s, xc);
        }
        *(float4*)(outp + (long)(y0 + o) * W + w0) = res;
    }
}

extern "C" void kernel_launch(void* const* d_in, const int* in_sizes, int n_in,
                              void* d_out, int out_size, void* d_ws, size_t ws_size,
                              hipStream_t stream)
{
    const float* x     = (const float*)d_in[0];
    const float* alpha = (const float*)d_in[1];
    float*       out   = (float*)d_out;

    const int grid = 8 * C * (H / 16);   // 512 images * 16 slabs = 8192
    adc_kernel<<<grid, 256, 0, stream>>>(x, alpha, out);
}